// Round 9
// baseline (335.057 us; speedup 1.0000x reference)
//
#include <hip/hip_runtime.h>
#include <hip/hip_bf16.h>

#define L_SZ 1024
#define P_SZ 2048
#define HID 256
#define NH 8
#define HD 32
#define NRBF 50
#define CH 32
#define NCH 64

typedef unsigned int uint32;
typedef _Float16 half2_t __attribute__((ext_vector_type(2)));
typedef __fp16 fp16x2_t __attribute__((ext_vector_type(2)));

__constant__ float kINV_SCALE = 0.17677669529663687f; // 1/sqrt(32)

static __device__ __forceinline__ unsigned short f2h(float f) {
    union { _Float16 h; unsigned short u; } x; x.h = (_Float16)f; return x.u;
}
static __device__ __forceinline__ float h2f(unsigned short u) {
    union { unsigned short u; _Float16 h; } x; x.u = u; return (float)x.h;
}
static __device__ __forceinline__ half2_t u2h2(uint32 u) {
    union { uint32 u; half2_t h; } x; x.u = u; return x.h;
}
static __device__ __forceinline__ half2_t pk2h(float a, float b) {
    union { fp16x2_t p; half2_t h; } x; x.p = __builtin_amdgcn_cvt_pkrtz(a, b); return x.h;
}

// async global->LDS, 16B per lane. LDS dest = wave-uniform base + lane*16.
static __device__ __forceinline__ void g2l16(const void* g, void* l) {
    __builtin_amdgcn_global_load_lds(
        (__attribute__((address_space(1))) void*)(void*)g,
        (__attribute__((address_space(3))) void*)l, 16, 0, 0);
}
static __device__ __forceinline__ void g2l4(const void* g, void* l) {
    __builtin_amdgcn_global_load_lds(
        (__attribute__((address_space(1))) void*)(void*)g,
        (__attribute__((address_space(3))) void*)l, 4, 0, 0);
}

#define WAITV0 asm volatile("s_waitcnt vmcnt(0)" ::: "memory")
#define WAITV1 asm volatile("s_waitcnt vmcnt(1)" ::: "memory")
#define CFENCE asm volatile("" ::: "memory")

// ---------------------------------------------------------------------------
// Kernel 1: Q = lig@Wq+bq (f32), K = prot@Wk+bk (f16), V = prot@Wv+bv (f16)
// ---------------------------------------------------------------------------
__global__ __launch_bounds__(64) void k_proj(
    const float* __restrict__ lig, const float* __restrict__ prot,
    const float* __restrict__ Wq, const float* __restrict__ bq,
    const float* __restrict__ Wk, const float* __restrict__ bk,
    const float* __restrict__ Wv, const float* __restrict__ bv,
    float* __restrict__ Qf, unsigned short* __restrict__ Kb,
    unsigned short* __restrict__ Vb)
{
    __shared__ float As[8 * HID];
    const int t = threadIdx.x;
    const int r0 = blockIdx.x * 8;

    const float* src; const float* W; const float* bias; int mode; int row0;
    if (r0 < L_SZ)            { src = lig  + (size_t)r0 * HID;               W = Wq; bias = bq; mode = 0; row0 = r0; }
    else if (r0 < L_SZ + P_SZ){ src = prot + (size_t)(r0 - L_SZ) * HID;      W = Wk; bias = bk; mode = 1; row0 = r0 - L_SZ; }
    else                      { src = prot + (size_t)(r0 - L_SZ - P_SZ)*HID; W = Wv; bias = bv; mode = 2; row0 = r0 - L_SZ - P_SZ; }

    float4* A4 = (float4*)As;
    const float4* S4 = (const float4*)src;
    #pragma unroll
    for (int j = 0; j < 8; ++j) A4[t + j * 64] = S4[t + j * 64];
    __syncthreads();

    float acc[8][4];
    #pragma unroll
    for (int r = 0; r < 8; ++r)
        #pragma unroll
        for (int c = 0; c < 4; ++c) acc[r][c] = 0.f;

    for (int k4 = 0; k4 < 64; ++k4) {
        float4 av[8];
        #pragma unroll
        for (int r = 0; r < 8; ++r) av[r] = A4[r * 64 + k4];
        #pragma unroll
        for (int kk = 0; kk < 4; ++kk) {
            const float* wr = W + (size_t)(k4 * 4 + kk) * HID + t;
            #pragma unroll
            for (int c = 0; c < 4; ++c) {
                float wv = wr[c * 64];
                #pragma unroll
                for (int r = 0; r < 8; ++r)
                    acc[r][c] += ((const float*)&av[r])[kk] * wv;
            }
        }
    }

    #pragma unroll
    for (int c = 0; c < 4; ++c) {
        const int col = t + c * 64;
        const float bb = bias[col];
        #pragma unroll
        for (int r = 0; r < 8; ++r) {
            float v = acc[r][c] + bb;
            size_t idx = (size_t)(row0 + r) * HID + col;
            if (mode == 0)      Qf[idx] = v;
            else if (mode == 1) Kb[idx] = f2h(v);
            else                Vb[idx] = f2h(v);
        }
    }
}

// ---------------------------------------------------------------------------
// Kernel 2: fused bias + QK^T + online softmax + PV + in-place finalize.
// One block per ligand row, 256 threads, 3 blocks/CU (LDS 47.7 KB).
// Raw f16 logits stream to the LOW half of this block's attn_out region
// (scatter u16 stores, vmcnt(1) keeps them outside the per-iter drain);
// softmax (m,s) online in registers; PV stages V (dbuf LDS) + per-chunk raw
// logits (tiny wbuf via dense g2l16); finalize rewrites the region in place
// f16-raw -> f32-weights in DESCENDING order (clobber-safe, 1 barrier/step).
// LDS: kv dbuf 2x16384 @0 | rbf dbuf 2x6400 @32768 | wbuf 2x1024 @45568 |
//      red[16] @47616. Total 47680 B.
// ---------------------------------------------------------------------------
__global__ __launch_bounds__(256, 3) void k_attn(
    const float* __restrict__ rbf, const float* __restrict__ Qf,
    const unsigned short* __restrict__ Kb, const unsigned short* __restrict__ Vb,
    const float* __restrict__ Wrbf, const float* __restrict__ brbf,
    float* __restrict__ attn_out, float* __restrict__ att_ws)
{
    __shared__ __align__(16) char sm[47680];
    char* rbfB  = sm + 32768;
    char* wbufB = sm + 45568;
    float* red  = (float*)(sm + 47616);

    const int t = threadIdx.x;
    const int lane = t & 63;
    const int wv = t >> 6;
    const int r = t & 31;     // protein row within chunk
    const int h = t >> 5;     // head 0..7
    const int l = blockIdx.x;
    char* aoB = (char*)attn_out + (size_t)l * (P_SZ * NH * 4);   // block's 64KB

    // stage one 32-row K or V chunk (16 KB), XOR-swizzled via pre-swizzled
    // global source (LDS dest stays linear). 4 loads per wave.
    auto stageKV = [&](const unsigned short* src, int c, char* dst) {
        const char* gb = (const char*)src + (size_t)c * (CH * 512);
        #pragma unroll
        for (int k = 0; k < 4; ++k) {
            int s = wv * 4 + k;               // 1KB slab 0..15
            int row = s * 2 + (lane >> 5);
            int off = ((lane & 31) ^ (row & 31)) << 4;
            g2l16(gb + row * 512 + off, dst + s * 1024);
        }
    };
    // stage one 32-row rbf chunk (6400 B), linear rows at r*200
    auto stageRBF = [&](int c, char* dst) {
        const char* gb = (const char*)rbf + (size_t)l * 409600 + (size_t)c * 6400;
        g2l16(gb + wv * 1024 + (lane << 4), dst + wv * 1024);
        if (wv == 0)      g2l16(gb + 4096 + (lane << 4), dst + 4096);
        else if (wv == 1) g2l16(gb + 5120 + (lane << 4), dst + 5120);
        else if (wv == 2) g2l4 (gb + 6144 + (lane << 2), dst + 6144);
    };

    // ---- per-thread preloads: Wrbf column h (25 half2), Q head h (16 half2)
    half2_t wrb[25];
    #pragma unroll
    for (int j = 0; j < 25; ++j)
        wrb[j] = pk2h(Wrbf[(2 * j) * NH + h], Wrbf[(2 * j + 1) * NH + h]);
    const float bh = brbf[h];

    half2_t qp[16];
    {
        const float* qq = Qf + (size_t)l * HID + h * HD;
        #pragma unroll
        for (int n = 0; n < 16; ++n)
            qp[n] = pk2h(qq[2 * n], qq[2 * n + 1]);
    }

    // ================= Pass 1: logits + online (m,s) ========================
    stageKV(Kb, 0, sm);
    stageRBF(0, rbfB);

    float mx = -3.0e38f, sme = 0.f;
    for (int c = 0; c < NCH; ++c) {
        if (c == 0) { WAITV0; } else { WAITV1; }   // allow logit store in flight
        __builtin_amdgcn_s_barrier();
        CFENCE;
        const int cb = c & 1;
        char* kb = sm + cb * 16384;
        char* rb = rbfB + cb * 6400;
        if (c + 1 < NCH) {                   // prefetch with a full iter of slack
            stageKV(Kb, c + 1, sm + (cb ^ 1) * 16384);
            stageRBF(c + 1, rbfB + (cb ^ 1) * 6400);
        }
        // bias = brbf[h] + rbf[l, p, :] . Wrbf[:, h]   (dual chains)
        float b0 = bh, b1 = 0.f;
        const char* rrow = rb + r * 200;
        #pragma unroll
        for (int j = 0; j < 12; ++j) {
            float2 v0 = *(const float2*)(rrow + (2 * j) * 8);
            float2 v1 = *(const float2*)(rrow + (2 * j + 1) * 8);
            b0 = __builtin_amdgcn_fdot2(pk2h(v0.x, v0.y), wrb[2 * j], b0, false);
            b1 = __builtin_amdgcn_fdot2(pk2h(v1.x, v1.y), wrb[2 * j + 1], b1, false);
        }
        {
            float2 v = *(const float2*)(rrow + 24 * 8);
            b0 = __builtin_amdgcn_fdot2(pk2h(v.x, v.y), wrb[24], b0, false);
        }
        // qk = Q[l,h,:] . K[p,h,:]   (dual chains)
        float qk0 = 0.f, qk1 = 0.f;
        const char* krow = kb + r * 512;
        #pragma unroll
        for (int jw = 0; jw < 2; ++jw) {
            int offA = (h * 64 + jw * 16) ^ (r << 4);
            int offB = (h * 64 + (jw + 2) * 16) ^ (r << 4);
            uint4 ka = *(const uint4*)(krow + offA);
            uint4 kbv = *(const uint4*)(krow + offB);
            qk0 = __builtin_amdgcn_fdot2(u2h2(ka.x),  qp[jw * 4 + 0], qk0, false);
            qk1 = __builtin_amdgcn_fdot2(u2h2(kbv.x), qp[(jw + 2) * 4 + 0], qk1, false);
            qk0 = __builtin_amdgcn_fdot2(u2h2(ka.y),  qp[jw * 4 + 1], qk0, false);
            qk1 = __builtin_amdgcn_fdot2(u2h2(kbv.y), qp[(jw + 2) * 4 + 1], qk1, false);
            qk0 = __builtin_amdgcn_fdot2(u2h2(ka.z),  qp[jw * 4 + 2], qk0, false);
            qk1 = __builtin_amdgcn_fdot2(u2h2(kbv.z), qp[(jw + 2) * 4 + 2], qk1, false);
            qk0 = __builtin_amdgcn_fdot2(u2h2(ka.w),  qp[jw * 4 + 3], qk0, false);
            qk1 = __builtin_amdgcn_fdot2(u2h2(kbv.w), qp[(jw + 2) * 4 + 3], qk1, false);
        }
        float lg = (qk0 + qk1) * kINV_SCALE + (b0 + b1);
        // online max/sum
        float nm = fmaxf(mx, lg);
        sme = sme * __expf(mx - nm) + __expf(lg - nm);
        mx = nm;
        // raw f16 logit -> low half of this block's attn_out region
        *(unsigned short*)(aoB + (c * CH + r) * 16 + h * 2) = f2h(lg);
    }

    // ---- merge (m,s) across the 32 lanes owning head h ----
    #pragma unroll
    for (int msk = 1; msk <= 16; msk <<= 1) {
        float om = __shfl_xor(mx, msk);
        float os = __shfl_xor(sme, msk);
        float nm = fmaxf(mx, om);
        sme = sme * __expf(mx - nm) + os * __expf(om - nm);
        mx = nm;
    }
    if ((t & 31) == 0) { red[h * 2] = mx; red[h * 2 + 1] = 1.f / sme; }

    __syncthreads();     // drains logit stores; publishes red; frees kv buffers

    // ================= Pass 2 (PV): V dbuf + raw logits via wbuf ============
    {
        stageKV(Vb, 0, sm);                            // V chunk 0
        if (wv == 0) g2l16(aoB + (lane << 4), wbufB);  // wbuf pair 0 (chunks 0,1)

        const int h3 = t >> 5;        // head
        const int dq = (t >> 3) & 3;  // dim quad (8 dims)
        const int ps = t & 7;         // p slice
        const int vinner = h3 * 64 + dq * 16;
        const float mh = red[h3 * 2];
        const float ih = red[h3 * 2 + 1];
        float acc[8] = {0.f, 0.f, 0.f, 0.f, 0.f, 0.f, 0.f, 0.f};
        for (int c = 0; c < NCH; ++c) {
            WAITV0;
            __builtin_amdgcn_s_barrier();
            CFENCE;
            const int cb = c & 1;
            char* vb = sm + cb * 16384;
            if (c + 1 < NCH) stageKV(Vb, c + 1, sm + (cb ^ 1) * 16384);
            if (((c & 1) == 0) && (c + 2 < NCH) && wv == 0) {
                int pr = (c >> 1) + 1;                 // stage wbuf pair
                g2l16(aoB + pr * 1024 + (lane << 4), wbufB + (pr & 1) * 1024);
            }
            const char* wp = wbufB + ((c >> 1) & 1) * 1024 + (c & 1) * 512;
            #pragma unroll
            for (int m = 0; m < 4; ++m) {
                int rr = m * 8 + ps;
                unsigned short lgr = *(const unsigned short*)(wp + rr * 16 + h3 * 2);
                float w = __expf(h2f(lgr) - mh) * ih;
                int off = vinner ^ (rr << 4);
                uint4 vvv = *(const uint4*)(vb + rr * 512 + off);
                half2_t x0 = u2h2(vvv.x), x1 = u2h2(vvv.y), x2 = u2h2(vvv.z), x3 = u2h2(vvv.w);
                acc[0] += w * (float)x0.x; acc[1] += w * (float)x0.y;
                acc[2] += w * (float)x1.x; acc[3] += w * (float)x1.y;
                acc[4] += w * (float)x2.x; acc[5] += w * (float)x2.y;
                acc[6] += w * (float)x3.x; acc[7] += w * (float)x3.y;
            }
        }
        #pragma unroll
        for (int d = 0; d < 8; ++d) {
            acc[d] += __shfl_xor(acc[d], 1);
            acc[d] += __shfl_xor(acc[d], 2);
            acc[d] += __shfl_xor(acc[d], 4);
        }
        if (ps == 0) {
            float* dst = att_ws + (size_t)l * HID + h3 * HD + dq * 8;
            *(float4*)dst       = make_float4(acc[0], acc[1], acc[2], acc[3]);
            *(float4*)(dst + 4) = make_float4(acc[4], acc[5], acc[6], acc[7]);
        }
    }
    __syncthreads();     // all wbuf reads of raw logits complete

    // ================= Pass 3: in-place finalize (descending) ===============
    // u32 j in [0,8192) holds f16 logits of (p=j>>2, heads 2(j&3), 2(j&3)+1);
    // writes float2 weights at byte 8j clobber u32s {2j,2j+1} — already
    // processed in descending order (n=0 guarded by the read->sync->write).
    {
        const int hA = 2 * (t & 3);
        const float mA = red[hA * 2],     iA = red[hA * 2 + 1];
        const float mB = red[hA * 2 + 2], iB = red[hA * 2 + 3];
        for (int n = 31; n >= 0; --n) {
            int j = t + n * 256;
            uint32 a = *(const uint32*)(aoB + 4 * j);
            float w0 = __expf(h2f((unsigned short)(a & 0xffffu)) - mA) * iA;
            float w1 = __expf(h2f((unsigned short)(a >> 16))     - mB) * iB;
            __syncthreads();
            *(float2*)(aoB + 8 * (size_t)j) = make_float2(w0, w1);
        }
    }
}

// ---------------------------------------------------------------------------
// Kernel 3: y = lig + attended@Wo + bo; LayerNorm
// ---------------------------------------------------------------------------
__global__ __launch_bounds__(256) void k_out(
    const float* __restrict__ att, const float* __restrict__ lig,
    const float* __restrict__ Wo, const float* __restrict__ bo,
    const float* __restrict__ gamma, const float* __restrict__ beta,
    float* __restrict__ out)
{
    __shared__ float a[HID];
    __shared__ float red[8];
    const int l = blockIdx.x, t = threadIdx.x;
    if (t < 64) ((float4*)a)[t] = ((const float4*)(att + (size_t)l * HID))[t];
    __syncthreads();

    float acc = bo[t];
    for (int k4 = 0; k4 < 64; ++k4) {
        float4 av = ((float4*)a)[k4];
        const float* wr = Wo + (size_t)(k4 * 4) * HID + t;
        acc += av.x * wr[0];
        acc += av.y * wr[HID];
        acc += av.z * wr[2 * HID];
        acc += av.w * wr[3 * HID];
    }
    float y = lig[(size_t)l * HID + t] + acc;

    float s = y, sq = y * y;
    #pragma unroll
    for (int msk = 1; msk < 64; msk <<= 1) {
        s  += __shfl_xor(s, msk);
        sq += __shfl_xor(sq, msk);
    }
    const int lane = t & 63, wvi = t >> 6;
    if (lane == 0) { red[wvi * 2] = s; red[wvi * 2 + 1] = sq; }
    __syncthreads();
    float ts = red[0] + red[2] + red[4] + red[6];
    float tq = red[1] + red[3] + red[5] + red[7];
    float mu = ts * (1.0f / HID);
    float var = tq * (1.0f / HID) - mu * mu;
    out[(size_t)l * HID + t] = (y - mu) * rsqrtf(var + 1e-5f) * gamma[t] + beta[t];
}

// ---------------------------------------------------------------------------
extern "C" void kernel_launch(void* const* d_in, const int* in_sizes, int n_in,
                              void* d_out, int out_size, void* d_ws, size_t ws_size,
                              hipStream_t stream)
{
    (void)in_sizes; (void)n_in; (void)out_size; (void)ws_size;

    const float* lig   = (const float*)d_in[0];
    const float* prot  = (const float*)d_in[1];
    const float* rbf   = (const float*)d_in[2];
    const float* Wq    = (const float*)d_in[5];
    const float* bq    = (const float*)d_in[6];
    const float* Wk    = (const float*)d_in[7];
    const float* bk    = (const float*)d_in[8];
    const float* Wv    = (const float*)d_in[9];
    const float* bv    = (const float*)d_in[10];
    const float* Wrbf  = (const float*)d_in[11];
    const float* brbf  = (const float*)d_in[12];
    const float* Wo    = (const float*)d_in[13];
    const float* bo    = (const float*)d_in[14];
    const float* gamma = (const float*)d_in[15];
    const float* beta  = (const float*)d_in[16];

    float* out0 = (float*)d_out;                          // [1024,256]
    float* attn = (float*)d_out + (size_t)L_SZ * HID;     // [1024,2048,8]

    char* ws = (char*)d_ws;
    float*          Qf     = (float*)ws;                          // 1 MB
    unsigned short* Kb     = (unsigned short*)(ws + (1u << 20));  // 1 MB
    unsigned short* Vb     = (unsigned short*)(ws + (2u << 20));  // 1 MB
    float*          att_ws = (float*)(ws + (3u << 20));           // 1 MB

    hipLaunchKernelGGL(k_proj, dim3((L_SZ + 2 * P_SZ) / 8), dim3(64), 0, stream,
                       lig, prot, Wq, bq, Wk, bk, Wv, bv, Qf, Kb, Vb);
    hipLaunchKernelGGL(k_attn, dim3(L_SZ), dim3(256), 0, stream,
                       rbf, Qf, Kb, Vb, Wrbf, brbf, attn, att_ws);
    hipLaunchKernelGGL(k_out, dim3(L_SZ), dim3(256), 0, stream,
                       att_ws, lig, Wo, bo, gamma, beta, out0);
}

// Round 10
// 273.766 us; speedup vs baseline: 1.2239x; 1.2239x over previous
//
#include <hip/hip_runtime.h>
#include <hip/hip_bf16.h>

#define L_SZ 1024
#define P_SZ 2048
#define HID 256
#define NH 8
#define HD 32
#define NRBF 50
#define CH 32
#define NCH 64

typedef unsigned int uint32;
typedef _Float16 half2_t __attribute__((ext_vector_type(2)));
typedef __fp16 fp16x2_t __attribute__((ext_vector_type(2)));

__constant__ float kINV_SCALE = 0.17677669529663687f; // 1/sqrt(32)

static __device__ __forceinline__ unsigned short f2h(float f) {
    union { _Float16 h; unsigned short u; } x; x.h = (_Float16)f; return x.u;
}
static __device__ __forceinline__ float h2f(unsigned short u) {
    union { unsigned short u; _Float16 h; } x; x.u = u; return (float)x.h;
}
static __device__ __forceinline__ half2_t u2h2(uint32 u) {
    union { uint32 u; half2_t h; } x; x.u = u; return x.h;
}
static __device__ __forceinline__ half2_t pk2h(float a, float b) {
    union { fp16x2_t p; half2_t h; } x; x.p = __builtin_amdgcn_cvt_pkrtz(a, b); return x.h;
}

// async global->LDS, 16B per lane. LDS dest = wave-uniform base + lane*16.
static __device__ __forceinline__ void g2l16(const void* g, void* l) {
    __builtin_amdgcn_global_load_lds(
        (__attribute__((address_space(1))) void*)(void*)g,
        (__attribute__((address_space(3))) void*)l, 16, 0, 0);
}
static __device__ __forceinline__ void g2l4(const void* g, void* l) {
    __builtin_amdgcn_global_load_lds(
        (__attribute__((address_space(1))) void*)(void*)g,
        (__attribute__((address_space(3))) void*)l, 4, 0, 0);
}

#define WAITV0 asm volatile("s_waitcnt vmcnt(0)" ::: "memory")
#define WAITV1 asm volatile("s_waitcnt vmcnt(1)" ::: "memory")
#define CFENCE asm volatile("" ::: "memory")

// ---------------------------------------------------------------------------
// Kernel 1: Q = lig@Wq+bq (f32), K = prot@Wk+bk (f16), V = prot@Wv+bv (f16)
// ---------------------------------------------------------------------------
__global__ __launch_bounds__(64) void k_proj(
    const float* __restrict__ lig, const float* __restrict__ prot,
    const float* __restrict__ Wq, const float* __restrict__ bq,
    const float* __restrict__ Wk, const float* __restrict__ bk,
    const float* __restrict__ Wv, const float* __restrict__ bv,
    float* __restrict__ Qf, unsigned short* __restrict__ Kb,
    unsigned short* __restrict__ Vb)
{
    __shared__ float As[8 * HID];
    const int t = threadIdx.x;
    const int r0 = blockIdx.x * 8;

    const float* src; const float* W; const float* bias; int mode; int row0;
    if (r0 < L_SZ)            { src = lig  + (size_t)r0 * HID;               W = Wq; bias = bq; mode = 0; row0 = r0; }
    else if (r0 < L_SZ + P_SZ){ src = prot + (size_t)(r0 - L_SZ) * HID;      W = Wk; bias = bk; mode = 1; row0 = r0 - L_SZ; }
    else                      { src = prot + (size_t)(r0 - L_SZ - P_SZ)*HID; W = Wv; bias = bv; mode = 2; row0 = r0 - L_SZ - P_SZ; }

    float4* A4 = (float4*)As;
    const float4* S4 = (const float4*)src;
    #pragma unroll
    for (int j = 0; j < 8; ++j) A4[t + j * 64] = S4[t + j * 64];
    __syncthreads();

    float acc[8][4];
    #pragma unroll
    for (int r = 0; r < 8; ++r)
        #pragma unroll
        for (int c = 0; c < 4; ++c) acc[r][c] = 0.f;

    for (int k4 = 0; k4 < 64; ++k4) {
        float4 av[8];
        #pragma unroll
        for (int r = 0; r < 8; ++r) av[r] = A4[r * 64 + k4];
        #pragma unroll
        for (int kk = 0; kk < 4; ++kk) {
            const float* wr = W + (size_t)(k4 * 4 + kk) * HID + t;
            #pragma unroll
            for (int c = 0; c < 4; ++c) {
                float wv = wr[c * 64];
                #pragma unroll
                for (int r = 0; r < 8; ++r)
                    acc[r][c] += ((const float*)&av[r])[kk] * wv;
            }
        }
    }

    #pragma unroll
    for (int c = 0; c < 4; ++c) {
        const int col = t + c * 64;
        const float bb = bias[col];
        #pragma unroll
        for (int r = 0; r < 8; ++r) {
            float v = acc[r][c] + bb;
            size_t idx = (size_t)(row0 + r) * HID + col;
            if (mode == 0)      Qf[idx] = v;
            else if (mode == 1) Kb[idx] = f2h(v);
            else                Vb[idx] = f2h(v);
        }
    }
}

// ---------------------------------------------------------------------------
// Kernel 2: SINGLE fused loop — bias + QK^T + online softmax + flash-PV.
// One block per ligand row, 256 threads, 2 blocks/CU (LDS 78.4 KB).
// Per chunk: stage K+V+rbf (dbuf), logit, online (m,s) w/ defer-max(8),
// O[32] += exp(lg-m)*V in registers; raw f16 logit -> low half of this
// block's attn_out region. Post-loop: shuffle-merge (m,s), LDS transpose-
// reduce O -> att_ws, then in-place descending finalize raw->f32 weights.
// LDS: K dbuf 2x16384 @0 | V dbuf 2x16384 @32768 | rbf dbuf 2x6400 @65536 |
//      red[16] @78336. Total 78400 B. otr (32KB) overlays K dbuf post-loop.
// ---------------------------------------------------------------------------
__global__ __launch_bounds__(256, 2) void k_attn(
    const float* __restrict__ rbf, const float* __restrict__ Qf,
    const unsigned short* __restrict__ Kb, const unsigned short* __restrict__ Vb,
    const float* __restrict__ Wrbf, const float* __restrict__ brbf,
    float* __restrict__ attn_out, float* __restrict__ att_ws)
{
    __shared__ __align__(16) char sm[78400];
    char* vBB  = sm + 32768;
    char* rbfB = sm + 65536;
    float* red = (float*)(sm + 78336);

    const int t = threadIdx.x;
    const int lane = t & 63;
    const int wv = t >> 6;
    const int r = t & 31;     // protein row within chunk
    const int h = t >> 5;     // head 0..7
    const int l = blockIdx.x;
    char* aoB = (char*)attn_out + (size_t)l * (P_SZ * NH * 4);   // block's 64KB

    // stage one 32-row K or V chunk (16 KB), XOR-swizzled via pre-swizzled
    // global source (LDS dest stays linear). 4 loads per wave.
    auto stageKV = [&](const unsigned short* src, int c, char* dst) {
        const char* gb = (const char*)src + (size_t)c * (CH * 512);
        #pragma unroll
        for (int k = 0; k < 4; ++k) {
            int s = wv * 4 + k;               // 1KB slab 0..15
            int row = s * 2 + (lane >> 5);
            int off = ((lane & 31) ^ (row & 31)) << 4;
            g2l16(gb + row * 512 + off, dst + s * 1024);
        }
    };
    // stage one 32-row rbf chunk (6400 B), linear rows at r*200
    auto stageRBF = [&](int c, char* dst) {
        const char* gb = (const char*)rbf + (size_t)l * 409600 + (size_t)c * 6400;
        g2l16(gb + wv * 1024 + (lane << 4), dst + wv * 1024);
        if (wv == 0)      g2l16(gb + 4096 + (lane << 4), dst + 4096);
        else if (wv == 1) g2l16(gb + 5120 + (lane << 4), dst + 5120);
        else if (wv == 2) g2l4 (gb + 6144 + (lane << 2), dst + 6144);
    };

    // ---- per-thread preloads: Wrbf column h (25 half2), Q head h (16 half2)
    half2_t wrb[25];
    #pragma unroll
    for (int j = 0; j < 25; ++j)
        wrb[j] = pk2h(Wrbf[(2 * j) * NH + h], Wrbf[(2 * j + 1) * NH + h]);
    const float bh = brbf[h];

    half2_t qp[16];
    {
        const float* qq = Qf + (size_t)l * HID + h * HD;
        #pragma unroll
        for (int n = 0; n < 16; ++n)
            qp[n] = pk2h(qq[2 * n], qq[2 * n + 1]);
    }

    // ================= Single fused loop ====================================
    stageKV(Kb, 0, sm);
    stageKV(Vb, 0, vBB);
    stageRBF(0, rbfB);

    float mx = -3.0e38f, sme = 0.f;
    float O[32];
    #pragma unroll
    for (int d = 0; d < 32; ++d) O[d] = 0.f;

    for (int c = 0; c < NCH; ++c) {
        if (c == 0) { WAITV0; } else { WAITV1; }   // leave raw store in flight
        __builtin_amdgcn_s_barrier();
        CFENCE;
        const int cb = c & 1;
        char* kb = sm + cb * 16384;
        char* vb = vBB + cb * 16384;
        char* rb = rbfB + cb * 6400;
        if (c + 1 < NCH) {                   // prefetch with a full iter of slack
            stageKV(Kb, c + 1, sm + (cb ^ 1) * 16384);
            stageKV(Vb, c + 1, vBB + (cb ^ 1) * 16384);
            stageRBF(c + 1, rbfB + (cb ^ 1) * 6400);
        }
        // bias = brbf[h] + rbf[l, p, :] . Wrbf[:, h]   (dual chains)
        float b0 = bh, b1 = 0.f;
        const char* rrow = rb + r * 200;
        #pragma unroll
        for (int j = 0; j < 12; ++j) {
            float2 v0 = *(const float2*)(rrow + (2 * j) * 8);
            float2 v1 = *(const float2*)(rrow + (2 * j + 1) * 8);
            b0 = __builtin_amdgcn_fdot2(pk2h(v0.x, v0.y), wrb[2 * j], b0, false);
            b1 = __builtin_amdgcn_fdot2(pk2h(v1.x, v1.y), wrb[2 * j + 1], b1, false);
        }
        {
            float2 v = *(const float2*)(rrow + 24 * 8);
            b0 = __builtin_amdgcn_fdot2(pk2h(v.x, v.y), wrb[24], b0, false);
        }
        // qk = Q[l,h,:] . K[p,h,:]   (dual chains)
        float qk0 = 0.f, qk1 = 0.f;
        const char* krow = kb + r * 512;
        #pragma unroll
        for (int jw = 0; jw < 2; ++jw) {
            int offA = (h * 64 + jw * 16) ^ (r << 4);
            int offB = (h * 64 + (jw + 2) * 16) ^ (r << 4);
            uint4 ka = *(const uint4*)(krow + offA);
            uint4 kbv = *(const uint4*)(krow + offB);
            qk0 = __builtin_amdgcn_fdot2(u2h2(ka.x),  qp[jw * 4 + 0], qk0, false);
            qk1 = __builtin_amdgcn_fdot2(u2h2(kbv.x), qp[(jw + 2) * 4 + 0], qk1, false);
            qk0 = __builtin_amdgcn_fdot2(u2h2(ka.y),  qp[jw * 4 + 1], qk0, false);
            qk1 = __builtin_amdgcn_fdot2(u2h2(kbv.y), qp[(jw + 2) * 4 + 1], qk1, false);
            qk0 = __builtin_amdgcn_fdot2(u2h2(ka.z),  qp[jw * 4 + 2], qk0, false);
            qk1 = __builtin_amdgcn_fdot2(u2h2(kbv.z), qp[(jw + 2) * 4 + 2], qk1, false);
            qk0 = __builtin_amdgcn_fdot2(u2h2(ka.w),  qp[jw * 4 + 3], qk0, false);
            qk1 = __builtin_amdgcn_fdot2(u2h2(kbv.w), qp[(jw + 2) * 4 + 3], qk1, false);
        }
        float lg = (qk0 + qk1) * kINV_SCALE + (b0 + b1);

        // online softmax with defer-max (THR=8): P bounded by e^8, f32-safe
        if (lg > mx + 8.0f) {
            float e = __expf(mx - lg);           // 0 on first trigger
            sme *= e;
            #pragma unroll
            for (int d = 0; d < 32; ++d) O[d] *= e;
            mx = lg;
        }
        float w = __expf(lg - mx);
        sme += w;

        // flash-PV: O += w * V[p, h*32 : h*32+32]
        const char* vrow = vb + r * 512;
        #pragma unroll
        for (int q = 0; q < 4; ++q) {
            int off = (h * 64 + q * 16) ^ (r << 4);
            uint4 vvv = *(const uint4*)(vrow + off);
            half2_t x0 = u2h2(vvv.x), x1 = u2h2(vvv.y), x2 = u2h2(vvv.z), x3 = u2h2(vvv.w);
            O[q * 8 + 0] += w * (float)x0.x; O[q * 8 + 1] += w * (float)x0.y;
            O[q * 8 + 2] += w * (float)x1.x; O[q * 8 + 3] += w * (float)x1.y;
            O[q * 8 + 4] += w * (float)x2.x; O[q * 8 + 5] += w * (float)x2.y;
            O[q * 8 + 6] += w * (float)x3.x; O[q * 8 + 7] += w * (float)x3.y;
        }

        // raw f16 logit -> low half of this block's attn_out region
        *(unsigned short*)(aoB + (c * CH + r) * 16 + h * 2) = f2h(lg);
    }
    WAITV0;                                      // drain raw logit stores

    // ---- merge (m,s) across the 32 lanes owning head h ----
    float mg = mx;
    #pragma unroll
    for (int msk = 1; msk <= 16; msk <<= 1) mg = fmaxf(mg, __shfl_xor(mg, msk));
    float e = __expf(mx - mg);
    sme *= e;
    #pragma unroll
    for (int msk = 1; msk <= 16; msk <<= 1) sme += __shfl_xor(sme, msk);
    float inv = 1.0f / sme;
    if (r == 0) { red[h * 2] = mg; red[h * 2 + 1] = inv; }
    const float scl = e * inv;                   // per-lane O scale

    __syncthreads();                             // K dbuf free; red published

    // ---- O transpose-reduce via LDS (rotate-swizzled, conflict-free) ----
    {
        float* otr = (float*)sm;                 // 32 KB over K dbuf
        #pragma unroll
        for (int d = 0; d < 32; ++d)
            otr[h * 1024 + r * 32 + ((d + r) & 31)] = O[d] * scl;
        __syncthreads();
        const int hh = t >> 5, dd = t & 31;
        float a = 0.f;
        #pragma unroll
        for (int rr = 0; rr < 32; ++rr)
            a += otr[hh * 1024 + rr * 32 + ((dd + rr) & 31)];
        att_ws[(size_t)l * HID + hh * HD + dd] = a;
    }

    // ---- in-place finalize raw f16 -> f32 weights (descending, R9-proven) --
    {
        const int hA = 2 * (t & 3);
        const float mA = red[hA * 2],     iA = red[hA * 2 + 1];
        const float mB = red[hA * 2 + 2], iB = red[hA * 2 + 3];
        for (int n = 31; n >= 0; --n) {
            int j = t + n * 256;
            uint32 a = *(const uint32*)(aoB + 4 * j);
            float w0 = __expf(h2f((unsigned short)(a & 0xffffu)) - mA) * iA;
            float w1 = __expf(h2f((unsigned short)(a >> 16))     - mB) * iB;
            __syncthreads();
            *(float2*)(aoB + 8 * (size_t)j) = make_float2(w0, w1);
        }
    }
}

// ---------------------------------------------------------------------------
// Kernel 3: y = lig + attended@Wo + bo; LayerNorm
// ---------------------------------------------------------------------------
__global__ __launch_bounds__(256) void k_out(
    const float* __restrict__ att, const float* __restrict__ lig,
    const float* __restrict__ Wo, const float* __restrict__ bo,
    const float* __restrict__ gamma, const float* __restrict__ beta,
    float* __restrict__ out)
{
    __shared__ float a[HID];
    __shared__ float red[8];
    const int l = blockIdx.x, t = threadIdx.x;
    if (t < 64) ((float4*)a)[t] = ((const float4*)(att + (size_t)l * HID))[t];
    __syncthreads();

    float acc = bo[t];
    for (int k4 = 0; k4 < 64; ++k4) {
        float4 av = ((float4*)a)[k4];
        const float* wr = Wo + (size_t)(k4 * 4) * HID + t;
        acc += av.x * wr[0];
        acc += av.y * wr[HID];
        acc += av.z * wr[2 * HID];
        acc += av.w * wr[3 * HID];
    }
    float y = lig[(size_t)l * HID + t] + acc;

    float s = y, sq = y * y;
    #pragma unroll
    for (int msk = 1; msk < 64; msk <<= 1) {
        s  += __shfl_xor(s, msk);
        sq += __shfl_xor(sq, msk);
    }
    const int lane = t & 63, wvi = t >> 6;
    if (lane == 0) { red[wvi * 2] = s; red[wvi * 2 + 1] = sq; }
    __syncthreads();
    float ts = red[0] + red[2] + red[4] + red[6];
    float tq = red[1] + red[3] + red[5] + red[7];
    float mu = ts * (1.0f / HID);
    float var = tq * (1.0f / HID) - mu * mu;
    out[(size_t)l * HID + t] = (y - mu) * rsqrtf(var + 1e-5f) * gamma[t] + beta[t];
}

// ---------------------------------------------------------------------------
extern "C" void kernel_launch(void* const* d_in, const int* in_sizes, int n_in,
                              void* d_out, int out_size, void* d_ws, size_t ws_size,
                              hipStream_t stream)
{
    (void)in_sizes; (void)n_in; (void)out_size; (void)ws_size;

    const float* lig   = (const float*)d_in[0];
    const float* prot  = (const float*)d_in[1];
    const float* rbf   = (const float*)d_in[2];
    const float* Wq    = (const float*)d_in[5];
    const float* bq    = (const float*)d_in[6];
    const float* Wk    = (const float*)d_in[7];
    const float* bk    = (const float*)d_in[8];
    const float* Wv    = (const float*)d_in[9];
    const float* bv    = (const float*)d_in[10];
    const float* Wrbf  = (const float*)d_in[11];
    const float* brbf  = (const float*)d_in[12];
    const float* Wo    = (const float*)d_in[13];
    const float* bo    = (const float*)d_in[14];
    const float* gamma = (const float*)d_in[15];
    const float* beta  = (const float*)d_in[16];

    float* out0 = (float*)d_out;                          // [1024,256]
    float* attn = (float*)d_out + (size_t)L_SZ * HID;     // [1024,2048,8]

    char* ws = (char*)d_ws;
    float*          Qf     = (float*)ws;                          // 1 MB
    unsigned short* Kb     = (unsigned short*)(ws + (1u << 20));  // 1 MB
    unsigned short* Vb     = (unsigned short*)(ws + (2u << 20));  // 1 MB
    float*          att_ws = (float*)(ws + (3u << 20));           // 1 MB

    hipLaunchKernelGGL(k_proj, dim3((L_SZ + 2 * P_SZ) / 8), dim3(64), 0, stream,
                       lig, prot, Wq, bq, Wk, bk, Wv, bv, Qf, Kb, Vb);
    hipLaunchKernelGGL(k_attn, dim3(L_SZ), dim3(256), 0, stream,
                       rbf, Qf, Kb, Vb, Wrbf, brbf, attn, att_ws);
    hipLaunchKernelGGL(k_out, dim3(L_SZ), dim3(256), 0, stream,
                       att_ws, lig, Wo, bo, gamma, beta, out0);
}